// Round 9
// baseline (165.256 us; speedup 1.0000x reference)
//
#include <hip/hip_runtime.h>
#include <stdint.h>
#include <math.h>

#define T_STEPS 4096
#define BATCH   256
#define NSEG    1024     // 4-step cert segments per batch (block-local = global)
#define CPITCH  9        // [seg][ch] pitch over 8 channels (bank spread)

// LIF step, threshold=1:  v'=alpha*v+xs; s=max(floor(v'),0); v=v'-s
__device__ __forceinline__ float lif_step(float& v, float xs, float alpha) {
    float vp = fmaf(alpha, v, xs);
    float fr = vp - floorf(vp);
    float vn = fminf(vp, fr);
    float s  = vp - vn;
    v = vn;
    return s;
}

__device__ __forceinline__ float ubf(uint32_t w, int k) {
    return (float)((w >> (k * 8)) & 0xffu);
}

// force a uniform value into an SGPR (weights): keeps VGPR live-set small
__device__ __forceinline__ float sgpr_f(float v) {
    return __uint_as_float(__builtin_amdgcn_readfirstlane(__float_as_uint(v)));
}

// round-UP u16 quantization of cert maxima (sound: decode >= true value;
// 65535 decodes +huge -> always flags).  Range [-8, 8), quantum 2.44e-4.
__device__ __forceinline__ unsigned short encq(float m) {
    int q = (int)ceilf(fmaf(m, 4096.0f, 32768.0f));
    q = q < 0 ? 0 : (q > 65534 ? 65535 : q);
    return (unsigned short)q;
}
__device__ __forceinline__ float decq(unsigned short q) {
    return (q == 65535) ? 1e30f : fmaf((float)q, 0.000244140625f, -8.0f);
}

__device__ __forceinline__ float dot16(const float wr[16],
    float4 c0, float4 c1, float4 c2, float4 c3)
{
    float p0 = fmaf(wr[1], c0.y, wr[0] * c0.x);
    p0 = fmaf(wr[2], c0.z, p0);  p0 = fmaf(wr[3], c0.w, p0);
    float p1 = fmaf(wr[5], c1.y, wr[4] * c1.x);
    p1 = fmaf(wr[6], c1.z, p1);  p1 = fmaf(wr[7], c1.w, p1);
    float p2 = fmaf(wr[9], c2.y, wr[8] * c2.x);
    p2 = fmaf(wr[10], c2.z, p2); p2 = fmaf(wr[11], c2.w, p2);
    float p3 = fmaf(wr[13], c3.y, wr[12] * c3.x);
    p3 = fmaf(wr[14], c3.z, p3); p3 = fmaf(wr[15], c3.w, p3);
    return (p0 + p1) + (p2 + p3);
}

// R22: CHANNEL-SPLIT blocks, 2 per CU.  Evidence: R20/R21 clean-traffic
// kernels sat at 61-70us with OccupancyPercent ~18% (vs 50% static) -- the
// wall is stragglers + phase gaps of ONE monolithic block per CU.  Channels
// are fully independent, so block (b, cg) owns 8 channels over the full
// timeline: no halo, composition starts at exact t=0/v=0, grid 512 = 2
// independent blocks/CU (LDS ~75KB each).  x is read by both siblings
// (second read L3-served).  m1 cert RESTORED (u16 round-up): the R18
// m0+alpha*vsu relaxation's 0.05 slack flagged ~3 channels/block and fed
// the serial repair straggler; the tight (1-vsu)*m0+vsu*m1 bound makes
// repair ~never fire.  Certs built in two 2-row passes (xr[8]=32 VGPRs, no
// spill at the 64-reg cap; combine in-place in LDS, wave-ordered DS).
// Tails (scan2/scan3) -> one flag-gated kernel; per-(b,cg) validity bits in
// flag1 gate which s1t channel rows scan2 may read.  bm1/flag1 pre-zeroed
// by hipMemsetAsync.
__global__ __launch_bounds__(512) void lif1(
    const float* __restrict__ x, const float* __restrict__ w1,
    float* __restrict__ out, uint8_t* __restrict__ s1t,
    uint8_t* __restrict__ bm1, int* __restrict__ flag1,
    float alpha, float one_m, float alpha4)
{
    const int tid = threadIdx.x;
    const int bh  = blockIdx.x;
    const int b   = bh >> 1;
    const int cg  = bh & 1;          // channel group: channels cg*8..cg*8+7
    const int wv  = tid >> 6;
    const int ln  = tid & 63;

    __shared__ float          endf[NSEG * CPITCH];   // 36 KiB  [s*9+c]
    __shared__ unsigned short m0q [NSEG * CPITCH];   // 18 KiB
    __shared__ unsigned short m1q [NSEG * CPITCH];   // 18 KiB
    __shared__ uint32_t       sh_badseg[8][32];      // 1 KiB
    __shared__ int            sh_badch;

    const float4* xq4 = (const float4*)(x + (size_t)b * T_STEPS * 16);

    if (tid == 0) sh_badch = 0;

    // ---- zero own half of out[b] (by t; halves disjoint across siblings) --
    float4* o4 = (float4*)(out + (size_t)b * T_STEPS * 10);   // 10240 float4
    float4 z4 = make_float4(0.f, 0.f, 0.f, 0.f);
#pragma unroll
    for (int i = 0; i < 10; ++i) o4[cg * 5120 + i * 512 + tid] = z4;

    const float a2 = alpha * alpha;
    const float a3 = a2 * alpha;
    const float a4 = a2 * a2;

    // ---- certs: thread handles segs {tid, 512+tid}, 8 channels each -------
#pragma unroll
    for (int ss = 0; ss < 2; ++ss) {
        const int s = ss * 512 + tid;
        // pass A: rows 0-1 (8 float4 = 32 VGPRs)
        {
            float4 xr[8];
#pragma unroll
            for (int q = 0; q < 8; ++q) xr[q] = xq4[s * 16 + q];
#pragma unroll 2
            for (int cl = 0; cl < 8; ++cl) {
                float wc[16];
#pragma unroll
                for (int i = 0; i < 16; ++i)
                    wc[i] = sgpr_f(w1[(cg * 8 + cl) * 16 + i]);
                float y0 = dot16(wc, xr[0], xr[1], xr[2], xr[3]);
                float y1 = dot16(wc, xr[4], xr[5], xr[6], xr[7]);
                float A0 = one_m * y0;
                float A1 = fmaf(alpha, A0, one_m * y1);
                endf[s * CPITCH + cl] = A1;
                m0q[s * CPITCH + cl] = encq(fmaxf(A0, A1));
                m1q[s * CPITCH + cl] = encq(fmaxf(A0 + alpha, A1 + a2));
            }
        }
        // pass B: rows 2-3; exact combine in place (same-thread DS ordered)
        {
            float4 xr[8];
#pragma unroll
            for (int q = 0; q < 8; ++q) xr[q] = xq4[s * 16 + 8 + q];
#pragma unroll 2
            for (int cl = 0; cl < 8; ++cl) {
                float wc[16];
#pragma unroll
                for (int i = 0; i < 16; ++i)
                    wc[i] = sgpr_f(w1[(cg * 8 + cl) * 16 + i]);
                float y2 = dot16(wc, xr[0], xr[1], xr[2], xr[3]);
                float y3 = dot16(wc, xr[4], xr[5], xr[6], xr[7]);
                float B0 = one_m * y2;
                float B1 = fmaf(alpha, B0, one_m * y3);
                float accA = endf[s * CPITCH + cl];
                float m0A  = decq(m0q[s * CPITCH + cl]);
                float m1A  = decq(m1q[s * CPITCH + cl]);
                float acc2 = fmaf(alpha, accA, B0);
                float acc3 = fmaf(a2, accA, B1);
                float m0 = fmaxf(m0A, fmaxf(acc2, acc3));
                float m1 = fmaxf(m1A, fmaxf(acc2 + a3, acc3 + a4));
                endf[s * CPITCH + cl] = acc3;
                m0q[s * CPITCH + cl] = encq(m0);
                m1q[s * CPITCH + cl] = encq(m1);
            }
        }
    }
    __syncthreads();   // all cert entries visible

    // ---- composition + certification: 8 ch x 8 eighths (64 lanes) ---------
    if (tid < 64) {
        const int c  = tid & 7;
        const int e8 = tid >> 3;
        const int s0 = e8 * 128;
        float vs = 0.0f;
        if (e8 > 0) {   // 40-seg warm-up: alpha4^40 = e^-8 = 3.4e-4 carry err
#pragma unroll 8
            for (int s = s0 - 40; s < s0; ++s)
                vs = fmaf(alpha4, vs, endf[s * CPITCH + c]);
        }
        uint32_t bw = 0;
        int bad = 0;
#pragma unroll 4
        for (int s = s0; s < s0 + 128; ++s) {
            float m0v = decq(m0q[s * CPITCH + c]);
            float m1v = decq(m1q[s * CPITCH + c]);
            float vsu = fminf(fmaxf(vs + 1e-3f, 0.0f), 1.0f);
            float bound = fmaf(1.0f - vsu, m0v, vsu * m1v);  // affine interp
            if (!(bound < 0.999f)) { bw |= 1u << (s & 31); bad = 1; }
            if ((s & 31) == 31) { sh_badseg[c][s >> 5] = bw; bw = 0; }
            vs = fmaf(alpha4, vs, endf[s * CPITCH + c]);
        }
        if (bad) atomicOr(&sh_badch, 1 << c);
    }
    __syncthreads();

    // ---- parallel exact repair for cert-bad channels (rare) ---------------
    const int badmask = sh_badch;
    if (badmask) {
        // dense-zero OUR 8 channels' s1t rows (scan2 gated by flag bits)
        uint4* sz = (uint4*)(s1t + ((size_t)b * 16 + cg * 8) * T_STEPS);
#pragma unroll
        for (int i = 0; i < 4; ++i) sz[i * 512 + tid] = make_uint4(0u,0u,0u,0u);
        __syncthreads();   // zeroing ordered before repair spike writes

        int m = badmask;
        for (int i = 0; i < wv; ++i) m &= m - 1;
        if (ln == 0 && m) {
            const int c = __ffs(m) - 1;              // local 0..7
            float wc[16];
#pragma unroll
            for (int i = 0; i < 16; ++i) wc[i] = w1[(cg * 8 + c) * 16 + i];
            uint8_t* op = s1t + ((size_t)b * 16 + cg * 8 + c) * T_STEPS;
            uint8_t* bmp = bm1 + (size_t)b * 256;
            float v = 0.0f;
            int any = 0;
            for (int w32 = 0; w32 < 32; ++w32) {
                uint32_t bwv = sh_badseg[c][w32];
                const int sb = w32 * 32;
                if (bwv == 0u) {
#pragma unroll 8
                    for (int q = 0; q < 32; ++q)
                        v = fmaf(alpha4, v, endf[(sb + q) * CPITCH + c]);
                } else {
                    for (int q = 0; q < 32; ++q) {
                        const int s = sb + q;
                        if (!((bwv >> q) & 1u)) {
                            v = fmaf(alpha4, v, endf[s * CPITCH + c]);
                            continue;
                        }
                        const float4* xr2 = xq4 + (size_t)s * 16;
                        uint32_t sw = 0u;
#pragma unroll
                        for (int j = 0; j < 4; ++j) {
                            float y = dot16(wc, xr2[j*4+0], xr2[j*4+1],
                                                 xr2[j*4+2], xr2[j*4+3]);
                            float sp = lif_step(v, one_m * y, alpha);
                            sw |= ((uint32_t)(int)sp) << (j * 8);
                        }
                        if (sw) {
                            *(uint32_t*)(op + s * 4) = sw;
                            bmp[s >> 2] = 1;     // cross-sibling byte race:
                            any = 1;             // same value 1, benign
                        }
                    }
                }
            }
            if (any) atomicOr(&flag1[b], 1 << cg);
        }
    }
}

// ---------------- tails: scan2 (s1t->s2t) then scan3 (s2t->out), per batch -
__global__ __launch_bounds__(64) void tails(
    const uint8_t* __restrict__ s1t, const float* __restrict__ w2,
    const float* __restrict__ w3, uint8_t* __restrict__ s2t,
    float* __restrict__ out, const uint8_t* __restrict__ bm1,
    const int* __restrict__ flag1, float alpha, float one_m)
{
    const int tid = threadIdx.x;
    const int b   = blockIdx.x;
    const int f   = flag1[b];
    if (!f) return;                       // no layer-1 spikes in this batch
    const bool v0 = (f & 1), v1 = (f & 2);

    __shared__ uint8_t sh_bm2[256];
    __shared__ int     sh_flag2;
    ((uint32_t*)sh_bm2)[tid] = 0u;
    if (tid == 0) sh_flag2 = 0;
    __syncthreads();

    // ---- layer-2: sparse scan s1t -> s2t (+ sh_bm2); 32 lanes -------------
    if (tid < 32) {
        const int c2 = tid;
        float wr2[16];
#pragma unroll
        for (int i = 0; i < 16; ++i) wr2[i] = one_m * w2[c2 * 16 + i];
        const uint8_t* sb1 = s1t + (size_t)b * 16 * T_STEPS;
        uint4* op2 = (uint4*)(s2t + ((size_t)b * 32 + c2) * T_STEPS);
        const uint4* bmv = (const uint4*)(bm1 + (size_t)b * 256);
        float v = 0.0f;
        for (int sb = 0; sb < 16; ++sb) {
            uint4 bm = bmv[sb];
            if ((bm.x | bm.y | bm.z | bm.w) == 0u) {
                if (v != 0.0f) {
                    for (int blk = 0; blk < 16 && v != 0.0f; ++blk) {
#pragma unroll
                        for (int j = 0; j < 16; ++j) v *= alpha;
                    }
                }
                continue;
            }
            for (int blk = 0; blk < 16; ++blk) {
                uint32_t d = (blk < 4) ? bm.x : (blk < 8) ? bm.y
                           : (blk < 12) ? bm.z : bm.w;
                uint32_t byte = (d >> ((blk & 3) * 8)) & 0xffu;
                if (byte == 0u) {
                    if (v != 0.0f) {
#pragma unroll
                        for (int j = 0; j < 16; ++j) v *= alpha;
                    }
                    continue;
                }
                const int tb = sb * 16 + blk;
                const int t0 = tb * 16;
                uint4 zz = make_uint4(0u,0u,0u,0u);
                uint4 S[16];
#pragma unroll
                for (int c = 0; c < 16; ++c) {
                    const bool valid = (c < 8) ? v0 : v1;  // cg validity gate
                    S[c] = valid ? *(const uint4*)(sb1 + (size_t)c * T_STEPS + t0)
                                 : zz;
                }
                uint32_t w[4] = {0u, 0u, 0u, 0u};
#pragma unroll
                for (int j = 0; j < 16; ++j) {
                    float xv[16];
#pragma unroll
                    for (int c = 0; c < 16; ++c) {
                        uint32_t dd = (j < 4) ? S[c].x : (j < 8) ? S[c].y
                                    : (j < 12) ? S[c].z : S[c].w;
                        xv[c] = ubf(dd, j & 3);
                    }
                    float p0 = fmaf(wr2[1], xv[1], wr2[0] * xv[0]);
                    p0 = fmaf(wr2[2], xv[2], p0);   p0 = fmaf(wr2[3], xv[3], p0);
                    float p1 = fmaf(wr2[5], xv[5], wr2[4] * xv[4]);
                    p1 = fmaf(wr2[6], xv[6], p1);   p1 = fmaf(wr2[7], xv[7], p1);
                    float p2 = fmaf(wr2[9], xv[9], wr2[8] * xv[8]);
                    p2 = fmaf(wr2[10], xv[10], p2); p2 = fmaf(wr2[11], xv[11], p2);
                    float p3 = fmaf(wr2[13], xv[13], wr2[12] * xv[12]);
                    p3 = fmaf(wr2[14], xv[14], p3); p3 = fmaf(wr2[15], xv[15], p3);
                    float xs = (p0 + p1) + (p2 + p3);
                    float s = lif_step(v, xs, alpha);
                    w[j >> 2] |= ((uint32_t)(int)s) << ((j & 3) * 8);
                }
                op2[tb] = make_uint4(w[0], w[1], w[2], w[3]);
                if (w[0] | w[1] | w[2] | w[3]) { sh_bm2[tb] = 1; sh_flag2 = 1; }
            }
        }
    }
    __syncthreads();   // s2t/sh_bm2/sh_flag2 visible

    // ---- layer-3: sparse scan s2t -> out (pre-zeroed); 16 lanes -----------
    if (sh_flag2 && tid < 16) {
        const int c3 = tid;
        const bool active = (c3 < 10);
        float wr3[32];
#pragma unroll
        for (int i = 0; i < 32; ++i)
            wr3[i] = active ? (one_m * w3[c3 * 32 + i]) : 0.0f;
        const uint8_t* sb2 = s2t + (size_t)b * 32 * T_STEPS;
        const uint4* bmv2 = (const uint4*)sh_bm2;
        float* ob = out + (size_t)b * T_STEPS * 10 + c3;
        float v = 0.0f;
        for (int sb = 0; sb < 16; ++sb) {
            uint4 bm = bmv2[sb];
            if ((bm.x | bm.y | bm.z | bm.w) == 0u) {
                if (v != 0.0f) {
                    for (int blk = 0; blk < 16 && v != 0.0f; ++blk) {
#pragma unroll
                        for (int j = 0; j < 16; ++j) v *= alpha;
                    }
                }
                continue;
            }
            for (int blk = 0; blk < 16; ++blk) {
                uint32_t d = (blk < 4) ? bm.x : (blk < 8) ? bm.y
                           : (blk < 12) ? bm.z : bm.w;
                uint32_t byte = (d >> ((blk & 3) * 8)) & 0xffu;
                if (byte == 0u) {
                    if (v != 0.0f) {
#pragma unroll
                        for (int j = 0; j < 16; ++j) v *= alpha;
                    }
                    continue;
                }
                const int t0 = (sb * 16 + blk) * 16;
                uint4 S[32];
#pragma unroll
                for (int c = 0; c < 32; ++c)
                    S[c] = *(const uint4*)(sb2 + (size_t)c * T_STEPS + t0);
#pragma unroll
                for (int j = 0; j < 16; ++j) {
                    float xv[32];
#pragma unroll
                    for (int c = 0; c < 32; ++c) {
                        uint32_t dd = (j < 4) ? S[c].x : (j < 8) ? S[c].y
                                    : (j < 12) ? S[c].z : S[c].w;
                        xv[c] = ubf(dd, j & 3);
                    }
                    float p0 = fmaf(wr3[1], xv[1], wr3[0] * xv[0]);
                    p0 = fmaf(wr3[2],  xv[2],  p0); p0 = fmaf(wr3[3],  xv[3],  p0);
                    p0 = fmaf(wr3[4],  xv[4],  p0); p0 = fmaf(wr3[5],  xv[5],  p0);
                    p0 = fmaf(wr3[6],  xv[6],  p0); p0 = fmaf(wr3[7],  xv[7],  p0);
                    float p1 = fmaf(wr3[9], xv[9], wr3[8] * xv[8]);
                    p1 = fmaf(wr3[10], xv[10], p1); p1 = fmaf(wr3[11], xv[11], p1);
                    p1 = fmaf(wr3[12], xv[12], p1); p1 = fmaf(wr3[13], xv[13], p1);
                    p1 = fmaf(wr3[14], xv[14], p1); p1 = fmaf(wr3[15], xv[15], p1);
                    float p2 = fmaf(wr3[17], xv[17], wr3[16] * xv[16]);
                    p2 = fmaf(wr3[18], xv[18], p2); p2 = fmaf(wr3[19], xv[19], p2);
                    p2 = fmaf(wr3[20], xv[20], p2); p2 = fmaf(wr3[21], xv[21], p2);
                    p2 = fmaf(wr3[22], xv[22], p2); p2 = fmaf(wr3[23], xv[23], p2);
                    float p3 = fmaf(wr3[25], xv[25], wr3[24] * xv[24]);
                    p3 = fmaf(wr3[26], xv[26], p3); p3 = fmaf(wr3[27], xv[27], p3);
                    p3 = fmaf(wr3[28], xv[28], p3); p3 = fmaf(wr3[29], xv[29], p3);
                    p3 = fmaf(wr3[30], xv[30], p3); p3 = fmaf(wr3[31], xv[31], p3);
                    float xs = (p0 + p1) + (p2 + p3);
                    float s = lif_step(v, xs, alpha);
                    if (active && s != 0.0f) ob[(size_t)(t0 + j) * 10] = s;
                }
            }
        }
    }
}

extern "C" void kernel_launch(void* const* d_in, const int* in_sizes, int n_in,
                              void* d_out, int out_size, void* d_ws, size_t ws_size,
                              hipStream_t stream)
{
    const float* data = (const float*)d_in[0];
    const float* w1   = (const float*)d_in[1];
    const float* w2   = (const float*)d_in[2];
    const float* w3   = (const float*)d_in[3];
    float* out = (float*)d_out;

    // ws layout (48 MiB + 65 KiB):
    //   [0, 16M)    s1t  u8 [256][16][4096] (zeroed per (b,cg) only when bad)
    //   [16M, 48M)  s2t  u8 [256][32][4096] (sparse: only bm2-set blocks)
    //   [48M, +64K) bm1  u8 [256][256]      (memset 0 each launch)
    //   [+64K,+65K) flag1 int[256]          (bit0 = cg0 spikes, bit1 = cg1)
    uint8_t* ws    = (uint8_t*)d_ws;
    uint8_t* s1t   = ws;
    uint8_t* s2t   = ws + (16u << 20);
    uint8_t* bm1   = ws + (48u << 20);
    int*     flag1 = (int*)(bm1 + (64u << 10));

    const float alpha  = expf(-1.0f / 20.0f);
    const float one_m  = 1.0f - alpha;
    const float alpha4 = expf(-4.0f / 20.0f);

    hipMemsetAsync(bm1, 0, (64u << 10) + 1024, stream);
    lif1 <<<BATCH * 2, 512, 0, stream>>>(data, w1, out, s1t, bm1, flag1,
                                         alpha, one_m, alpha4);
    tails<<<BATCH,     64, 0, stream>>>(s1t, w2, w3, s2t, out, bm1, flag1,
                                        alpha, one_m);
}